// Round 3
// baseline (702.912 us; speedup 1.0000x reference)
//
#include <hip/hip_runtime.h>

// SelfAttention (non-local block), B=4, C=128, H=W=64, N=HW=4096.
// Outputs: [x + relu(bn(conv(attn@g)))] (2,097,152 f32)  ++  attn (67,108,864 f32)
//
// Layout fact: torch .view(B,-1,C) of a (B,C,H,W) buffer makes the (C,HW)
// conv output buffer literally the (N,C) row-major matrix (n*128+c == o*4096+s).
//
// Round-2 changes vs round-1 (598 us): 4-wave cooperative sweep blocks
// (16 waves/CU vs 8, VGPR <=128 vs ~180), S = M + ln(L) stat folding,
// defer-max (1 exp/elem) in sweep1, full-line nontemporal attn stores via
// LDS transpose, bigger prep/outconv grids.  (Round 3 = re-run; round-2
// bench hit a GPU-acquisition timeout, no data.)

typedef _Float16 f16;
typedef __attribute__((ext_vector_type(8))) _Float16 f16x8;
typedef __attribute__((ext_vector_type(4))) float f32x4;

#define CC 128
#define NN 4096
#define BB 4
#define NC (NN * CC)
#define EPS_BN 1e-5f

// workspace offsets (bytes); total 36 MB
#define OFF_THETA (0ull)
#define OFF_PHI   (4ull << 20)
#define OFF_G     (8ull << 20)
#define OFF_GT    (12ull << 20)
#define OFF_PSTAT (8ull << 20)                  // aliases G (dead after k_tr_g)
#define OFF_STAT  (OFF_PSTAT + (1ull << 19))    // [B][N] f32 = 64 KB
#define OFF_TPART (16ull << 20)                 // [4][B][N][C] f16 = 16 MB
#define OFF_T     (32ull << 20)                 // [B][N][C] f16 = 4 MB

// ---------------------------------------------------------------------------
// K1: fused 1x1 conv + bias + relu + BN for theta/phi/g. 1 spatial/thread.
__global__ __launch_bounds__(256) void k_prep(
    const float* __restrict__ x,
    const float* __restrict__ t_w, const float* __restrict__ t_b,
    const float* __restrict__ t_ga, const float* __restrict__ t_be,
    const float* __restrict__ t_me, const float* __restrict__ t_va,
    const float* __restrict__ p_w, const float* __restrict__ p_b,
    const float* __restrict__ p_ga, const float* __restrict__ p_be,
    const float* __restrict__ p_me, const float* __restrict__ p_va,
    const float* __restrict__ g_w, const float* __restrict__ g_b,
    const float* __restrict__ g_ga, const float* __restrict__ g_be,
    const float* __restrict__ g_me, const float* __restrict__ g_va,
    f16* __restrict__ th, f16* __restrict__ ph, f16* __restrict__ gh)
{
  const int s  = blockIdx.x * 256 + threadIdx.x;
  const int o0 = blockIdx.y * 8;
  const int b  = blockIdx.z;
  const float* xb = x + (size_t)b * NC;

  float acc[3][8];
#pragma unroll
  for (int br = 0; br < 3; ++br)
#pragma unroll
    for (int j = 0; j < 8; ++j) acc[br][j] = 0.f;

#pragma unroll 4
  for (int c = 0; c < CC; ++c) {
    float xv = xb[c * NN + s];
#pragma unroll
    for (int j = 0; j < 8; ++j) {
      acc[0][j] += t_w[(o0 + j) * CC + c] * xv;   // uniform -> s_load
      acc[1][j] += p_w[(o0 + j) * CC + c] * xv;
      acc[2][j] += g_w[(o0 + j) * CC + c] * xv;
    }
  }

  f16* outs[3] = { th, ph, gh };
  const float* bi[3] = { t_b,  p_b,  g_b  };
  const float* ga[3] = { t_ga, p_ga, g_ga };
  const float* be[3] = { t_be, p_be, g_be };
  const float* me[3] = { t_me, p_me, g_me };
  const float* va[3] = { t_va, p_va, g_va };
#pragma unroll
  for (int br = 0; br < 3; ++br) {
#pragma unroll
    for (int j = 0; j < 8; ++j) {
      int o = o0 + j;
      float inv = ga[br][o] * rsqrtf(va[br][o] + EPS_BN);
      float add = be[br][o] - me[br][o] * inv;
      float y = fmaxf(acc[br][j] + bi[br][o], 0.f) * inv + add;
      outs[br][(size_t)b * NC + (size_t)o * NN + s] = (f16)y;
    }
  }
}

// ---------------------------------------------------------------------------
// K2: transpose g (N rows, C cols) -> gt (C rows, N cols), fp16.
__global__ __launch_bounds__(256) void k_tr_g(const f16* __restrict__ gh,
                                              f16* __restrict__ gt)
{
  __shared__ f16 tile[64][72];
  const int b   = blockIdx.z;
  const int m0  = blockIdx.x * 64;
  const int c20 = blockIdx.y * 64;
  const f16* gb_ = gh + (size_t)b * NC;
  f16* gtb = gt + (size_t)b * NC;
  const int t = threadIdx.x;
  {
    const int mr = t >> 2, co = (t & 3) * 16;
    f16x8 v0 = *(const f16x8*)(gb_ + (size_t)(m0 + mr) * CC + c20 + co);
    f16x8 v1 = *(const f16x8*)(gb_ + (size_t)(m0 + mr) * CC + c20 + co + 8);
#pragma unroll
    for (int j = 0; j < 8; ++j) tile[co + j][mr] = v0[j];
#pragma unroll
    for (int j = 0; j < 8; ++j) tile[co + 8 + j][mr] = v1[j];
  }
  __syncthreads();
  {
    const int cr = t >> 2, mo = (t & 3) * 16;
    f16x8 w0 = *(const f16x8*)(&tile[cr][mo]);
    f16x8 w1 = *(const f16x8*)(&tile[cr][mo + 8]);
    *(f16x8*)(gtb + (size_t)(c20 + cr) * NN + m0 + mo)     = w0;
    *(f16x8*)(gtb + (size_t)(c20 + cr) * NN + m0 + mo + 8) = w1;
  }
}

// ---------------------------------------------------------------------------
// Sweeps: 4-wave blocks, 64 rows x 1024-col chunk. grid 1024 = B*4chunk*64rb.
// b = bid&3 with bid%8 XCD round-robin -> one batch per XCD (phi/gt L2-resident).
// MFMA 16x16x32 f16 maps: A: l -> A[l&15][(l>>4)*8+e]; B: l -> B[(l>>4)*8+e][l&15];
// D: l,r -> D[(l>>4)*4+r][l&15].
__global__ __launch_bounds__(256, 4) void k_sweep1(
    const f16* __restrict__ th, const f16* __restrict__ ph_,
    float2* __restrict__ pstat)
{
  const int bid = blockIdx.x;
  const int b = bid & 3, chunk = (bid >> 2) & 3, rb = bid >> 4;
  const int tid = threadIdx.x, w = tid >> 6;
  const int lane = tid & 63, lr = lane & 15, lg = lane >> 4;
  const int wn0 = rb * 64 + w * 16;
  const f16* tb_ = th  + (size_t)b * NC;
  const f16* pb_ = ph_ + (size_t)b * NC;

  f16x8 a[4];
#pragma unroll
  for (int kk = 0; kk < 4; ++kk)
    a[kk] = *(const f16x8*)(tb_ + (size_t)(wn0 + lr) * CC + kk * 32 + lg * 8);

  float m[4], l[4];
#pragma unroll
  for (int r = 0; r < 4; ++r) { m[r] = -1e30f; l[r] = 0.f; }

  const int mbase = chunk * 1024;
  for (int t = 0; t < 64; ++t) {
    const int mc = mbase + t * 16;
    f16x8 bf[4];
#pragma unroll
    for (int kk = 0; kk < 4; ++kk)
      bf[kk] = *(const f16x8*)(pb_ + (size_t)(mc + lr) * CC + kk * 32 + lg * 8);
    f32x4 d = {0.f, 0.f, 0.f, 0.f};
#pragma unroll
    for (int kk = 0; kk < 4; ++kk)
      d = __builtin_amdgcn_mfma_f32_16x16x32_f16(a[kk], bf[kk], d, 0, 0, 0);
#pragma unroll
    for (int r = 0; r < 4; ++r) {          // defer-max: 1 exp in the common path
      float dd = d[r] - m[r];
      if (dd > 8.f) { l[r] = l[r] * __expf(-dd) + 1.f; m[r] = d[r]; }
      else          { l[r] += __expf(dd); }
    }
  }
#pragma unroll
  for (int off = 1; off < 16; off <<= 1) {
#pragma unroll
    for (int r = 0; r < 4; ++r) {
      float mo = __shfl_xor(m[r], off);
      float lo = __shfl_xor(l[r], off);
      float mn = fmaxf(m[r], mo);
      l[r] = l[r] * __expf(m[r] - mn) + lo * __expf(mo - mn);
      m[r] = mn;
    }
  }
  if (lr == 0) {
#pragma unroll
    for (int r = 0; r < 4; ++r)
      pstat[(size_t)(chunk * BB + b) * NN + wn0 + lg * 4 + r] = make_float2(m[r], l[r]);
  }
}

__global__ void k_merge_stats(const float2* __restrict__ pstat,
                              float* __restrict__ stat)
{
  int i = blockIdx.x * 256 + threadIdx.x;          // 0..16383 = b*N + n
  float2 s0 = pstat[i];
  float2 s1 = pstat[(size_t)BB * NN + i];
  float2 s2 = pstat[(size_t)2 * BB * NN + i];
  float2 s3 = pstat[(size_t)3 * BB * NN + i];
  float m = fmaxf(fmaxf(s0.x, s1.x), fmaxf(s2.x, s3.x));
  float L = s0.y * __expf(s0.x - m) + s1.y * __expf(s1.x - m) +
            s2.y * __expf(s2.x - m) + s3.y * __expf(s3.x - m);
  stat[i] = m + __logf(L);                         // P = exp(z - S)
}

#define PSTRIDE 36                                  // f32; 16B-aligned rows, 2-way banks
#define PSZ (64 * PSTRIDE)

__global__ __launch_bounds__(256, 4) void k_sweep2(
    const f16* __restrict__ th, const f16* __restrict__ ph_,
    const f16* __restrict__ gt, const float* __restrict__ stat,
    float* __restrict__ attn, f16* __restrict__ tpart)
{
  __shared__ float plds[2 * PSZ];                   // double-buffered P tile (64x32)
  const int bid = blockIdx.x;
  const int b = bid & 3, chunk = (bid >> 2) & 3, rb = bid >> 4;
  const int tid = threadIdx.x, w = tid >> 6;
  const int lane = tid & 63, lr = lane & 15, lg = lane >> 4;
  const int n0 = rb * 64, wn0 = n0 + w * 16;
  const f16* tb_ = th  + (size_t)b * NC;
  const f16* pb_ = ph_ + (size_t)b * NC;
  const f16* gb_ = gt  + (size_t)b * NC;

  f16x8 aq[4];
#pragma unroll
  for (int kk = 0; kk < 4; ++kk)
    aq[kk] = *(const f16x8*)(tb_ + (size_t)(wn0 + lr) * CC + kk * 32 + lg * 8);

  float S[4];
#pragma unroll
  for (int r = 0; r < 4; ++r) S[r] = stat[(size_t)b * NN + wn0 + lg * 4 + r];

  f32x4 tacc[8];
#pragma unroll
  for (int ct = 0; ct < 8; ++ct) tacc[ct] = (f32x4){0.f, 0.f, 0.f, 0.f};

  float* attn_b = attn + (size_t)b * NN * NN;
  const int mbase = chunk * 1024;
  const int arow = tid >> 2, acol = (tid & 3) * 8;  // cooperative attn-store map

  for (int grp = 0; grp < 32; ++grp) {
    const int m0 = mbase + grp * 32;
    float* pb = plds + (grp & 1) * PSZ;
    // ---- QK^T for this wave's 16 rows x 32 cols, P = exp(z - S)
#pragma unroll
    for (int sub = 0; sub < 2; ++sub) {
      const int mc = m0 + sub * 16;
      f16x8 bf[4];
#pragma unroll
      for (int kk = 0; kk < 4; ++kk)
        bf[kk] = *(const f16x8*)(pb_ + (size_t)(mc + lr) * CC + kk * 32 + lg * 8);
      f32x4 d = {0.f, 0.f, 0.f, 0.f};
#pragma unroll
      for (int kk = 0; kk < 4; ++kk)
        d = __builtin_amdgcn_mfma_f32_16x16x32_f16(aq[kk], bf[kk], d, 0, 0, 0);
#pragma unroll
      for (int r = 0; r < 4; ++r)
        pb[(w * 16 + lg * 4 + r) * PSTRIDE + sub * 16 + lr] = __expf(d[r] - S[r]);
    }
    __syncthreads();   // single barrier per grp; safe with double buffer
    // ---- cooperative full-line reads for attn store (rows of all 4 waves)
    f32x4 o0 = *(const f32x4*)&pb[arow * PSTRIDE + acol];
    f32x4 o1 = *(const f32x4*)&pb[arow * PSTRIDE + acol + 4];
    // ---- PV A-fragment: row l&15, k = lg*8+e over the 32 cols
    f32x4 q0 = *(const f32x4*)&pb[(w * 16 + lr) * PSTRIDE + lg * 8];
    f32x4 q1 = *(const f32x4*)&pb[(w * 16 + lr) * PSTRIDE + lg * 8 + 4];
    f16x8 pa;
#pragma unroll
    for (int e = 0; e < 4; ++e) { pa[e] = (f16)q0[e]; pa[4 + e] = (f16)q1[e]; }
    // ---- nontemporal attn store (256B/4-lane-group, full cache lines)
    float* ab = attn_b + (size_t)(n0 + arow) * NN + m0 + acol;
    __builtin_nontemporal_store(o0, (f32x4*)ab);
    __builtin_nontemporal_store(o1, (f32x4*)(ab + 4));
    // ---- PV: tacc[ct] += P(16x32) @ G(32 x 16c)
#pragma unroll
    for (int ct = 0; ct < 8; ++ct) {
      f16x8 gbf = *(const f16x8*)(gb_ + (size_t)(ct * 16 + lr) * NN + m0 + lg * 8);
      tacc[ct] = __builtin_amdgcn_mfma_f32_16x16x32_f16(pa, gbf, tacc[ct], 0, 0, 0);
    }
  }

  f16* tp = tpart + (size_t)(chunk * BB + b) * NC;
#pragma unroll
  for (int ct = 0; ct < 8; ++ct)
#pragma unroll
    for (int r = 0; r < 4; ++r)
      tp[(size_t)(wn0 + lg * 4 + r) * CC + ct * 16 + lr] = (f16)tacc[ct][r];
}

__global__ void k_merge_t(const f16* __restrict__ tpart, f16* __restrict__ t_h)
{
  int i = blockIdx.x * 256 + threadIdx.x;          // 0..262143, 8 halfs each
  size_t base = (size_t)i * 8;
  f16x8 v0 = *(const f16x8*)(tpart + base);
  f16x8 v1 = *(const f16x8*)(tpart + (size_t)BB * NC + base);
  f16x8 v2 = *(const f16x8*)(tpart + (size_t)2 * BB * NC + base);
  f16x8 v3 = *(const f16x8*)(tpart + (size_t)3 * BB * NC + base);
  f16x8 o;
#pragma unroll
  for (int j = 0; j < 8; ++j)
    o[j] = (f16)((float)v0[j] + (float)v1[j] + (float)v2[j] + (float)v3[j]);
  *(f16x8*)(t_h + base) = o;
}

// ---------------------------------------------------------------------------
// K7: out conv + BN + relu + residual. t (N,C) flat == t_fm (C,HW) flat.
__global__ __launch_bounds__(256) void k_outconv(
    const float* __restrict__ x, const f16* __restrict__ t_h,
    const float* __restrict__ o_w, const float* __restrict__ o_b,
    const float* __restrict__ o_ga, const float* __restrict__ o_be,
    const float* __restrict__ o_me, const float* __restrict__ o_va,
    float* __restrict__ out0)
{
  const int s  = blockIdx.x * 256 + threadIdx.x;
  const int o0 = blockIdx.y * 8;
  const int b  = blockIdx.z;
  const f16* tb_ = t_h + (size_t)b * NC;
  float acc[8];
#pragma unroll
  for (int j = 0; j < 8; ++j) acc[j] = 0.f;

#pragma unroll 4
  for (int c = 0; c < CC; ++c) {
    float tv = (float)tb_[c * NN + s];
#pragma unroll
    for (int j = 0; j < 8; ++j)
      acc[j] += o_w[(o0 + j) * CC + c] * tv;       // uniform -> s_load
  }
#pragma unroll
  for (int j = 0; j < 8; ++j) {
    int o = o0 + j;
    float inv = o_ga[o] * rsqrtf(o_va[o] + EPS_BN);
    float add = o_be[o] - o_me[o] * inv;
    float y = fmaxf((acc[j] + o_b[o]) * inv + add, 0.f);
    size_t idx = (size_t)(b * CC + o) * NN + s;
    out0[idx] = x[idx] + y;
  }
}

// ---------------------------------------------------------------------------
extern "C" void kernel_launch(void* const* d_in, const int* in_sizes, int n_in,
                              void* d_out, int out_size, void* d_ws, size_t ws_size,
                              hipStream_t stream)
{
  (void)in_sizes; (void)n_in; (void)out_size; (void)ws_size;
  const float* x    = (const float*)d_in[0];
  const float* t_w  = (const float*)d_in[1];
  const float* t_b  = (const float*)d_in[2];
  const float* t_ga = (const float*)d_in[3];
  const float* t_be = (const float*)d_in[4];
  const float* t_me = (const float*)d_in[5];
  const float* t_va = (const float*)d_in[6];
  const float* p_w  = (const float*)d_in[7];
  const float* p_b  = (const float*)d_in[8];
  const float* p_ga = (const float*)d_in[9];
  const float* p_be = (const float*)d_in[10];
  const float* p_me = (const float*)d_in[11];
  const float* p_va = (const float*)d_in[12];
  const float* g_w  = (const float*)d_in[13];
  const float* g_b  = (const float*)d_in[14];
  const float* g_ga = (const float*)d_in[15];
  const float* g_be = (const float*)d_in[16];
  const float* g_me = (const float*)d_in[17];
  const float* g_va = (const float*)d_in[18];
  const float* o_w  = (const float*)d_in[19];
  const float* o_b  = (const float*)d_in[20];
  const float* o_ga = (const float*)d_in[21];
  const float* o_be = (const float*)d_in[22];
  const float* o_me = (const float*)d_in[23];
  const float* o_va = (const float*)d_in[24];

  char* ws = (char*)d_ws;
  f16*    th    = (f16*)   (ws + OFF_THETA);
  f16*    ph    = (f16*)   (ws + OFF_PHI);
  f16*    gh    = (f16*)   (ws + OFF_G);
  f16*    gt    = (f16*)   (ws + OFF_GT);
  float2* pstat = (float2*)(ws + OFF_PSTAT);   // aliases gh (dead after k_tr_g)
  float*  stat  = (float*) (ws + OFF_STAT);
  f16*    tpart = (f16*)   (ws + OFF_TPART);
  f16*    t_h   = (f16*)   (ws + OFF_T);

  float* out0 = (float*)d_out;
  float* attn = out0 + (size_t)BB * CC * NN;

  k_prep<<<dim3(16, 16, BB), 256, 0, stream>>>(
      x, t_w, t_b, t_ga, t_be, t_me, t_va,
         p_w, p_b, p_ga, p_be, p_me, p_va,
         g_w, g_b, g_ga, g_be, g_me, g_va, th, ph, gh);
  k_tr_g<<<dim3(64, 2, BB), 256, 0, stream>>>(gh, gt);
  k_sweep1<<<1024, 256, 0, stream>>>(th, ph, pstat);
  k_merge_stats<<<64, 256, 0, stream>>>(pstat, stat);
  k_sweep2<<<1024, 256, 0, stream>>>(th, ph, gt, stat, attn, tpart);
  k_merge_t<<<1024, 256, 0, stream>>>(tpart, t_h);
  k_outconv<<<dim3(16, 16, BB), 256, 0, stream>>>(
      x, t_h, o_w, o_b, o_ga, o_be, o_me, o_va, out0);
}

// Round 4
// 543.748 us; speedup vs baseline: 1.2927x; 1.2927x over previous
//
#include <hip/hip_runtime.h>

// SelfAttention (non-local block), B=4, C=128, H=W=64, N=HW=4096.
// Outputs: [x + relu(bn(conv(attn@g)))] (2,097,152 f32)  ++  attn (67,108,864 f32)
//
// Layout fact: torch .view(B,-1,C) of a (B,C,H,W) buffer makes the (C,HW)
// conv output buffer literally the (N,C) row-major matrix (n*128+c == o*4096+s).
//
// Round-4 changes vs round-3 (702 us; sweep2 257 us write-pattern-bound:
// MfmaUtil 5%, VALU 7%, HBM 21%, WRITE 414 MB w/ 1.45x amplification):
//  - 32 rows/wave (halves phi/gt L2 re-reads vs 16 rows/wave)
//  - per-wave private LDS, NO __syncthreads anywhere in sweeps
//  - P accumulated in LDS, attn flushed in 512B-contiguous runs (vs 128B)
//  - tpart stored via LDS bounce as 1KB-contiguous f16 (vs 2B scatter)
//  - k_merge_stats folded into sweep2 prologue

typedef _Float16 f16;
typedef __attribute__((ext_vector_type(8))) _Float16 f16x8;
typedef __attribute__((ext_vector_type(4))) float f32x4;

#define CC 128
#define NN 4096
#define BB 4
#define NC (NN * CC)
#define EPS_BN 1e-5f

// workspace offsets (bytes); total 36 MB
#define OFF_THETA (0ull)
#define OFF_PHI   (4ull << 20)
#define OFF_G     (8ull << 20)
#define OFF_GT    (12ull << 20)
#define OFF_PSTAT (8ull << 20)    // aliases G (dead after k_tr_g)
#define OFF_TPART (16ull << 20)   // [4][B][N][C] f16 = 16 MB
#define OFF_T     (32ull << 20)   // [B][N][C] f16 = 4 MB

// ---------------------------------------------------------------------------
// K1: fused 1x1 conv + bias + relu + BN for theta/phi/g. 1 spatial/thread.
__global__ __launch_bounds__(256) void k_prep(
    const float* __restrict__ x,
    const float* __restrict__ t_w, const float* __restrict__ t_b,
    const float* __restrict__ t_ga, const float* __restrict__ t_be,
    const float* __restrict__ t_me, const float* __restrict__ t_va,
    const float* __restrict__ p_w, const float* __restrict__ p_b,
    const float* __restrict__ p_ga, const float* __restrict__ p_be,
    const float* __restrict__ p_me, const float* __restrict__ p_va,
    const float* __restrict__ g_w, const float* __restrict__ g_b,
    const float* __restrict__ g_ga, const float* __restrict__ g_be,
    const float* __restrict__ g_me, const float* __restrict__ g_va,
    f16* __restrict__ th, f16* __restrict__ ph, f16* __restrict__ gh)
{
  const int s  = blockIdx.x * 256 + threadIdx.x;
  const int o0 = blockIdx.y * 8;
  const int b  = blockIdx.z;
  const float* xb = x + (size_t)b * NC;

  float acc[3][8];
#pragma unroll
  for (int br = 0; br < 3; ++br)
#pragma unroll
    for (int j = 0; j < 8; ++j) acc[br][j] = 0.f;

#pragma unroll 4
  for (int c = 0; c < CC; ++c) {
    float xv = xb[c * NN + s];
#pragma unroll
    for (int j = 0; j < 8; ++j) {
      acc[0][j] += t_w[(o0 + j) * CC + c] * xv;   // uniform -> s_load
      acc[1][j] += p_w[(o0 + j) * CC + c] * xv;
      acc[2][j] += g_w[(o0 + j) * CC + c] * xv;
    }
  }

  f16* outs[3] = { th, ph, gh };
  const float* bi[3] = { t_b,  p_b,  g_b  };
  const float* ga[3] = { t_ga, p_ga, g_ga };
  const float* be[3] = { t_be, p_be, g_be };
  const float* me[3] = { t_me, p_me, g_me };
  const float* va[3] = { t_va, p_va, g_va };
#pragma unroll
  for (int br = 0; br < 3; ++br) {
#pragma unroll
    for (int j = 0; j < 8; ++j) {
      int o = o0 + j;
      float inv = ga[br][o] * rsqrtf(va[br][o] + EPS_BN);
      float add = be[br][o] - me[br][o] * inv;
      float y = fmaxf(acc[br][j] + bi[br][o], 0.f) * inv + add;
      outs[br][(size_t)b * NC + (size_t)o * NN + s] = (f16)y;
    }
  }
}

// ---------------------------------------------------------------------------
// K2: transpose g (N rows, C cols) -> gt (C rows, N cols), fp16.
__global__ __launch_bounds__(256) void k_tr_g(const f16* __restrict__ gh,
                                              f16* __restrict__ gt)
{
  __shared__ f16 tile[64][72];
  const int b   = blockIdx.z;
  const int m0  = blockIdx.x * 64;
  const int c20 = blockIdx.y * 64;
  const f16* gb_ = gh + (size_t)b * NC;
  f16* gtb = gt + (size_t)b * NC;
  const int t = threadIdx.x;
  {
    const int mr = t >> 2, co = (t & 3) * 16;
    f16x8 v0 = *(const f16x8*)(gb_ + (size_t)(m0 + mr) * CC + c20 + co);
    f16x8 v1 = *(const f16x8*)(gb_ + (size_t)(m0 + mr) * CC + c20 + co + 8);
#pragma unroll
    for (int j = 0; j < 8; ++j) tile[co + j][mr] = v0[j];
#pragma unroll
    for (int j = 0; j < 8; ++j) tile[co + 8 + j][mr] = v1[j];
  }
  __syncthreads();
  {
    const int cr = t >> 2, mo = (t & 3) * 16;
    f16x8 w0 = *(const f16x8*)(&tile[cr][mo]);
    f16x8 w1 = *(const f16x8*)(&tile[cr][mo + 8]);
    *(f16x8*)(gtb + (size_t)(c20 + cr) * NN + m0 + mo)     = w0;
    *(f16x8*)(gtb + (size_t)(c20 + cr) * NN + m0 + mo + 8) = w1;
  }
}

// ---------------------------------------------------------------------------
// Sweeps: 4 independent waves/block (no barriers), 32 rows/wave, 1024-col
// chunk. grid 512 = rb(32) x chunk(4) x b(4); b = bid&3 -> one batch per XCD
// (bid%8 round-robins XCDs; phi/theta/gt of one batch = 3 MB < 4 MB L2).
// MFMA 16x16x32 f16 maps: A: l -> A[l&15][(l>>4)*8+e]; B: l -> B[(l>>4)*8+e][l&15];
// D: l,r -> D[(l>>4)*4+r][l&15].
__global__ __launch_bounds__(256, 4) void k_sweep1(
    const f16* __restrict__ th, const f16* __restrict__ ph_,
    float2* __restrict__ pstat)
{
  const int bid = blockIdx.x;
  const int b = bid & 3, chunk = (bid >> 2) & 3, rb = bid >> 4;
  const int tid = threadIdx.x, w = tid >> 6;
  const int lane = tid & 63, lr = lane & 15, lg = lane >> 4;
  const int n0 = rb * 128 + w * 32;
  const f16* tb_ = th  + (size_t)b * NC;
  const f16* pb_ = ph_ + (size_t)b * NC;

  f16x8 a[2][4];
#pragma unroll
  for (int tr = 0; tr < 2; ++tr)
#pragma unroll
    for (int kk = 0; kk < 4; ++kk)
      a[tr][kk] = *(const f16x8*)(tb_ + (size_t)(n0 + tr * 16 + lr) * CC + kk * 32 + lg * 8);

  float m[2][4], l[2][4];
#pragma unroll
  for (int tr = 0; tr < 2; ++tr)
#pragma unroll
    for (int r = 0; r < 4; ++r) { m[tr][r] = -1e30f; l[tr][r] = 0.f; }

  const int mbase = chunk * 1024;
#pragma unroll 2
  for (int t = 0; t < 64; ++t) {
    const int mc = mbase + t * 16;
    f16x8 bf[4];
#pragma unroll
    for (int kk = 0; kk < 4; ++kk)
      bf[kk] = *(const f16x8*)(pb_ + (size_t)(mc + lr) * CC + kk * 32 + lg * 8);
#pragma unroll
    for (int tr = 0; tr < 2; ++tr) {
      f32x4 d = {0.f, 0.f, 0.f, 0.f};
#pragma unroll
      for (int kk = 0; kk < 4; ++kk)
        d = __builtin_amdgcn_mfma_f32_16x16x32_f16(a[tr][kk], bf[kk], d, 0, 0, 0);
#pragma unroll
      for (int r = 0; r < 4; ++r) {          // defer-max: 1 exp common path
        float dd = d[r] - m[tr][r];
        if (dd > 8.f) { l[tr][r] = l[tr][r] * __expf(-dd) + 1.f; m[tr][r] = d[r]; }
        else          { l[tr][r] += __expf(dd); }
      }
    }
  }
#pragma unroll
  for (int off = 1; off < 16; off <<= 1) {
#pragma unroll
    for (int tr = 0; tr < 2; ++tr)
#pragma unroll
      for (int r = 0; r < 4; ++r) {
        float mo = __shfl_xor(m[tr][r], off);
        float lo = __shfl_xor(l[tr][r], off);
        float mn = fmaxf(m[tr][r], mo);
        l[tr][r] = l[tr][r] * __expf(m[tr][r] - mn) + lo * __expf(mo - mn);
        m[tr][r] = mn;
      }
  }
  if (lr == 0) {
#pragma unroll
    for (int tr = 0; tr < 2; ++tr)
#pragma unroll
      for (int r = 0; r < 4; ++r)
        pstat[(size_t)(chunk * BB + b) * NN + n0 + tr * 16 + lg * 4 + r] =
            make_float2(m[tr][r], l[tr][r]);
  }
}

// ---------------------------------------------------------------------------
#define LSTR 132   // f32 row stride in LDS P-buffer (132%32=4 banks: 2-way max)

__global__ __launch_bounds__(256, 2) void k_sweep2(
    const f16* __restrict__ th, const f16* __restrict__ ph_,
    const f16* __restrict__ gt, const float2* __restrict__ pstat,
    float* __restrict__ attn, f16* __restrict__ tpart)
{
  __shared__ float plds[4 * 32 * LSTR];             // 66 KB; per-wave private
  const int bid = blockIdx.x;
  const int b = bid & 3, chunk = (bid >> 2) & 3, rb = bid >> 4;
  const int tid = threadIdx.x, w = tid >> 6;
  const int lane = tid & 63, lr = lane & 15, lg = lane >> 4;
  const int n0 = rb * 128 + w * 32;
  const f16* tb_ = th  + (size_t)b * NC;
  const f16* pb_ = ph_ + (size_t)b * NC;
  const f16* gb_ = gt  + (size_t)b * NC;
  float* pw = plds + w * 32 * LSTR;

  f16x8 aq[2][4];
#pragma unroll
  for (int tr = 0; tr < 2; ++tr)
#pragma unroll
    for (int kk = 0; kk < 4; ++kk)
      aq[tr][kk] = *(const f16x8*)(tb_ + (size_t)(n0 + tr * 16 + lr) * CC + kk * 32 + lg * 8);

  // inline stat merge: S = M + ln(L) per row (redundant across lr lanes; L2 hits)
  float S[2][4];
#pragma unroll
  for (int tr = 0; tr < 2; ++tr)
#pragma unroll
    for (int r = 0; r < 4; ++r) {
      const int row = n0 + tr * 16 + lg * 4 + r;
      float mM = -1e30f, LL = 0.f;
#pragma unroll
      for (int ch = 0; ch < 4; ++ch) {
        float2 ps = pstat[(size_t)(ch * BB + b) * NN + row];
        float mn = fmaxf(mM, ps.x);
        LL = LL * __expf(mM - mn) + ps.y * __expf(ps.x - mn);
        mM = mn;
      }
      S[tr][r] = mM + __logf(LL);
    }

  f32x4 tacc[2][8];
#pragma unroll
  for (int tr = 0; tr < 2; ++tr)
#pragma unroll
    for (int ct = 0; ct < 8; ++ct) tacc[tr][ct] = (f32x4){0.f, 0.f, 0.f, 0.f};

  float* attn_b = attn + (size_t)b * NN * NN;
  const int mbase = chunk * 1024;

  for (int blk = 0; blk < 8; ++blk) {               // 8 x 128-col flush blocks
#pragma unroll
    for (int gi = 0; gi < 4; ++gi) {                // 4 x 32-col groups
      const int m0 = mbase + (blk * 4 + gi) * 32;
      // ---- QK^T, P = exp(z - S) -> LDS
#pragma unroll
      for (int sub = 0; sub < 2; ++sub) {
        const int mc = m0 + sub * 16;
        f16x8 bf[4];
#pragma unroll
        for (int kk = 0; kk < 4; ++kk)
          bf[kk] = *(const f16x8*)(pb_ + (size_t)(mc + lr) * CC + kk * 32 + lg * 8);
#pragma unroll
        for (int tr = 0; tr < 2; ++tr) {
          f32x4 d = {0.f, 0.f, 0.f, 0.f};
#pragma unroll
          for (int kk = 0; kk < 4; ++kk)
            d = __builtin_amdgcn_mfma_f32_16x16x32_f16(aq[tr][kk], bf[kk], d, 0, 0, 0);
#pragma unroll
          for (int r = 0; r < 4; ++r)
            pw[(tr * 16 + lg * 4 + r) * LSTR + gi * 32 + sub * 16 + lr] =
                __expf(d[r] - S[tr][r]);
        }
      }
      // ---- PV A-fragment from this wave's own LDS (lgkmcnt-ordered, no barrier)
      f16x8 pa[2];
#pragma unroll
      for (int tr = 0; tr < 2; ++tr) {
        f32x4 q0 = *(const f32x4*)&pw[(tr * 16 + lr) * LSTR + gi * 32 + lg * 8];
        f32x4 q1 = *(const f32x4*)&pw[(tr * 16 + lr) * LSTR + gi * 32 + lg * 8 + 4];
#pragma unroll
        for (int e = 0; e < 4; ++e) { pa[tr][e] = (f16)q0[e]; pa[tr][4 + e] = (f16)q1[e]; }
      }
      // ---- PV: tacc[tr][ct] += P(16x32) @ G(32x16c)
#pragma unroll
      for (int ct = 0; ct < 8; ++ct) {
        f16x8 gbf = *(const f16x8*)(gb_ + (size_t)(ct * 16 + lr) * NN + m0 + lg * 8);
#pragma unroll
        for (int tr = 0; tr < 2; ++tr)
          tacc[tr][ct] = __builtin_amdgcn_mfma_f32_16x16x32_f16(pa[tr], gbf, tacc[tr][ct], 0, 0, 0);
      }
    }
    // ---- flush 32 rows x 128 cols: 512B contiguous per row, 2 rows/instr
    const int fr = lane >> 5, fc = (lane & 31) * 4;
#pragma unroll
    for (int j = 0; j < 32; j += 2) {
      f32x4 v = *(const f32x4*)&pw[(j + fr) * LSTR + fc];
      __builtin_nontemporal_store(v,
          (f32x4*)(attn_b + (size_t)(n0 + j + fr) * NN + mbase + blk * 128 + fc));
    }
  }

  // ---- tpart via LDS bounce -> 1KB-contiguous coalesced f16 stores
  f16* pwh = (f16*)pw;                              // stride 264 f16
#pragma unroll
  for (int tr = 0; tr < 2; ++tr)
#pragma unroll
    for (int ct = 0; ct < 8; ++ct)
#pragma unroll
      for (int r = 0; r < 4; ++r)
        pwh[(tr * 16 + lg * 4 + r) * 264 + ct * 16 + lr] = (f16)tacc[tr][ct][r];
  f16* tp = tpart + (size_t)(chunk * BB + b) * NC;
#pragma unroll
  for (int j = 0; j < 32; j += 4) {
    const int row = j + (lane >> 4), colh = (lane & 15) * 8;
    f16x8 v = *(const f16x8*)&pwh[row * 264 + colh];
    *(f16x8*)(tp + (size_t)(n0 + row) * CC + colh) = v;
  }
}

__global__ void k_merge_t(const f16* __restrict__ tpart, f16* __restrict__ t_h)
{
  int i = blockIdx.x * 256 + threadIdx.x;           // 0..262143, 8 halfs each
  size_t base = (size_t)i * 8;
  f16x8 v0 = *(const f16x8*)(tpart + base);
  f16x8 v1 = *(const f16x8*)(tpart + (size_t)BB * NC + base);
  f16x8 v2 = *(const f16x8*)(tpart + (size_t)2 * BB * NC + base);
  f16x8 v3 = *(const f16x8*)(tpart + (size_t)3 * BB * NC + base);
  f16x8 o;
#pragma unroll
  for (int j = 0; j < 8; ++j)
    o[j] = (f16)((float)v0[j] + (float)v1[j] + (float)v2[j] + (float)v3[j]);
  *(f16x8*)(t_h + base) = o;
}

// ---------------------------------------------------------------------------
// K7: out conv + BN + relu + residual. t (N,C) flat == t_fm (C,HW) flat.
__global__ __launch_bounds__(256) void k_outconv(
    const float* __restrict__ x, const f16* __restrict__ t_h,
    const float* __restrict__ o_w, const float* __restrict__ o_b,
    const float* __restrict__ o_ga, const float* __restrict__ o_be,
    const float* __restrict__ o_me, const float* __restrict__ o_va,
    float* __restrict__ out0)
{
  const int s  = blockIdx.x * 256 + threadIdx.x;
  const int o0 = blockIdx.y * 8;
  const int b  = blockIdx.z;
  const f16* tb_ = t_h + (size_t)b * NC;
  float acc[8];
#pragma unroll
  for (int j = 0; j < 8; ++j) acc[j] = 0.f;

#pragma unroll 4
  for (int c = 0; c < CC; ++c) {
    float tv = (float)tb_[c * NN + s];
#pragma unroll
    for (int j = 0; j < 8; ++j)
      acc[j] += o_w[(o0 + j) * CC + c] * tv;        // uniform -> s_load
  }
#pragma unroll
  for (int j = 0; j < 8; ++j) {
    int o = o0 + j;
    float inv = o_ga[o] * rsqrtf(o_va[o] + EPS_BN);
    float add = o_be[o] - o_me[o] * inv;
    float y = fmaxf((acc[j] + o_b[o]) * inv + add, 0.f);
    size_t idx = (size_t)(b * CC + o) * NN + s;
    out0[idx] = x[idx] + y;
  }
}

// ---------------------------------------------------------------------------
extern "C" void kernel_launch(void* const* d_in, const int* in_sizes, int n_in,
                              void* d_out, int out_size, void* d_ws, size_t ws_size,
                              hipStream_t stream)
{
  (void)in_sizes; (void)n_in; (void)out_size; (void)ws_size;
  const float* x    = (const float*)d_in[0];
  const float* t_w  = (const float*)d_in[1];
  const float* t_b  = (const float*)d_in[2];
  const float* t_ga = (const float*)d_in[3];
  const float* t_be = (const float*)d_in[4];
  const float* t_me = (const float*)d_in[5];
  const float* t_va = (const float*)d_in[6];
  const float* p_w  = (const float*)d_in[7];
  const float* p_b  = (const float*)d_in[8];
  const float* p_ga = (const float*)d_in[9];
  const float* p_be = (const float*)d_in[10];
  const float* p_me = (const float*)d_in[11];
  const float* p_va = (const float*)d_in[12];
  const float* g_w  = (const float*)d_in[13];
  const float* g_b  = (const float*)d_in[14];
  const float* g_ga = (const float*)d_in[15];
  const float* g_be = (const float*)d_in[16];
  const float* g_me = (const float*)d_in[17];
  const float* g_va = (const float*)d_in[18];
  const float* o_w  = (const float*)d_in[19];
  const float* o_b  = (const float*)d_in[20];
  const float* o_ga = (const float*)d_in[21];
  const float* o_be = (const float*)d_in[22];
  const float* o_me = (const float*)d_in[23];
  const float* o_va = (const float*)d_in[24];

  char* ws = (char*)d_ws;
  f16*    th    = (f16*)   (ws + OFF_THETA);
  f16*    ph    = (f16*)   (ws + OFF_PHI);
  f16*    gh    = (f16*)   (ws + OFF_G);
  f16*    gt    = (f16*)   (ws + OFF_GT);
  float2* pstat = (float2*)(ws + OFF_PSTAT);   // aliases gh (dead after k_tr_g)
  f16*    tpart = (f16*)   (ws + OFF_TPART);
  f16*    t_h   = (f16*)   (ws + OFF_T);

  float* out0 = (float*)d_out;
  float* attn = out0 + (size_t)BB * CC * NN;

  k_prep<<<dim3(16, 16, BB), 256, 0, stream>>>(
      x, t_w, t_b, t_ga, t_be, t_me, t_va,
         p_w, p_b, p_ga, p_be, p_me, p_va,
         g_w, g_b, g_ga, g_be, g_me, g_va, th, ph, gh);
  k_tr_g<<<dim3(64, 2, BB), 256, 0, stream>>>(gh, gt);
  k_sweep1<<<512, 256, 0, stream>>>(th, ph, pstat);
  k_sweep2<<<512, 256, 0, stream>>>(th, ph, gt, pstat, attn, tpart);
  k_merge_t<<<1024, 256, 0, stream>>>(tpart, t_h);
  k_outconv<<<dim3(16, 16, BB), 256, 0, stream>>>(
      x, t_h, o_w, o_b, o_ga, o_be, o_me, o_va, out0);
}